// Round 1
// baseline (1505.791 us; speedup 1.0000x reference)
//
#include <hip/hip_runtime.h>

// Readout (segment mean): out[g, :] = mean(atom_hiddens[start_g : start_g+size_g, :])
// D = 300 floats per row = 75 float4 per row. One thread per output float4.

#define D4 75  // 300 / 4

__global__ void Readout_68822555951732_kernel(const float4* __restrict__ atoms,
                                              const int* __restrict__ a_scope,
                                              float4* __restrict__ out,
                                              int n_out4) {
    int idx = blockIdx.x * blockDim.x + threadIdx.x;
    if (idx >= n_out4) return;

    int g  = idx / D4;
    int d4 = idx - g * D4;

    int start = a_scope[2 * g];
    int size  = a_scope[2 * g + 1];

    const float4* p = atoms + (long)start * D4 + d4;

    float4 acc = make_float4(0.f, 0.f, 0.f, 0.f);
#pragma unroll 4
    for (int i = 0; i < size; ++i) {
        float4 v = p[(long)i * D4];
        acc.x += v.x;
        acc.y += v.y;
        acc.z += v.z;
        acc.w += v.w;
    }

    float inv = 1.0f / (float)(size > 0 ? size : 1);
    acc.x *= inv;
    acc.y *= inv;
    acc.z *= inv;
    acc.w *= inv;

    out[idx] = acc;
}

extern "C" void kernel_launch(void* const* d_in, const int* in_sizes, int n_in,
                              void* d_out, int out_size, void* d_ws, size_t ws_size,
                              hipStream_t stream) {
    const float4* atoms   = (const float4*)d_in[0];  // 1e6 x 300 fp32
    const int*    a_scope = (const int*)d_in[1];     // 50000 x 2 int32 (start, size)
    float4*       out     = (float4*)d_out;          // 50000 x 300 fp32

    int n_out4 = out_size / 4;  // 3,750,000
    int block  = 256;
    int grid   = (n_out4 + block - 1) / block;
    Readout_68822555951732_kernel<<<grid, block, 0, stream>>>(atoms, a_scope, out, n_out4);
}